// Round 8
// baseline (799.790 us; speedup 1.0000x reference)
//
#include <hip/hip_runtime.h>

#define SEQ 512
#define BATCH 256
#define INDIM 256
#define MLP 128
#define M_ROWS (SEQ * BATCH)        // 131072
#define PRE_STRIDE 136              // 128 mlp-pre + 4 gate-pre + 4 pad
#define AUX_OFF ((size_t)M_ROWS * PRE_STRIDE)  // in floats

// ws layout (floats): [0, AUX_OFF) PRE; [AUX_OFF, +136) aux;
// [AUX_OFF+160, ...) bf16 weight pairs: Bt_hi (18432 f = 36864 ushort),
// Bt_lo (18432 f), bias144 (144 f). Bt layout: [n(144)][k(256)] bf16,
// n<128 = W1 col n, n=128..131 = Wf/Wi/Wg/Wo input rows, n>=132 = 0.
#define BT_OFF (AUX_OFF + 160)

typedef __attribute__((ext_vector_type(8))) short short8v;
typedef __attribute__((ext_vector_type(4))) float f32x4;

__device__ __forceinline__ unsigned short bf16_rtne(float f) {
  unsigned u = __float_as_uint(f);
  unsigned r = u + 0x7FFFu + ((u >> 16) & 1u);
  return (unsigned short)(r >> 16);
}
__device__ __forceinline__ void cvt2(float f, unsigned short& h,
                                     unsigned short& l) {
  h = bf16_rtne(f);
  l = bf16_rtne(f - __uint_as_float((unsigned)h << 16));
}

// ---------------------------------------------------------------------------
// Kernel 1: prep — aux col-sums (unchanged) + one-time bf16 hi/lo conversion
// of [W1 | Wf Wi Wg Wo | 0pad] into Bt (n-major, k contiguous) + bias144.
// ---------------------------------------------------------------------------
__global__ __launch_bounds__(256) void prep_kernel(
    const float* __restrict__ W1,
    const float* __restrict__ Wf, const float* __restrict__ Wi,
    const float* __restrict__ Wg, const float* __restrict__ Wo,
    const float* __restrict__ bf, const float* __restrict__ bi,
    const float* __restrict__ bg, const float* __restrict__ bo,
    const float* __restrict__ b1, float* __restrict__ aux,
    float* __restrict__ btbase) {
  const int tid = threadIdx.x;
  if (tid < 128) {
    float s = 0.f;
    for (int k = 0; k < 256; ++k) s += W1[(size_t)(256 + k) * 128 + tid];
    aux[tid] = s;
  } else if (tid < 132) {
    const int g = tid - 128;
    const float* w = (g == 0) ? Wf : (g == 1) ? Wi : (g == 2) ? Wg : Wo;
    float s = 0.f;
    for (int k = 0; k < 256; ++k) s += w[256 + k];
    aux[128 + g] = s;
  } else if (tid < 136) {
    const int g = tid - 132;
    const float* bp = (g == 0) ? bf : (g == 1) ? bi : (g == 2) ? bg : bo;
    aux[132 + g] = bp[0];
  }

  unsigned short* bth = (unsigned short*)btbase;
  unsigned short* btl = (unsigned short*)(btbase + 18432);
  float* b144 = btbase + 36864;
  for (int tau = tid; tau < 576; tau += 256) {
    const int n = tau >> 2, q = tau & 3;
    const float* wg = (n == 129) ? Wi : (n == 130) ? Wg : (n == 131) ? Wo : Wf;
    for (int k = q * 64; k < q * 64 + 64; ++k) {
      const float v = (n < 128) ? W1[(size_t)k * 128 + n]
                                : ((n < 132) ? wg[k] : 0.f);
      unsigned short h, l;
      cvt2(v, h, l);
      bth[n * 256 + k] = h;
      btl[n * 256 + k] = l;
    }
  }
  if (tid < 144) {
    const float bv = (tid < 128) ? b1[tid]
                   : (tid == 128) ? bf[0] : (tid == 129) ? bi[0]
                   : (tid == 130) ? bg[0] : (tid == 131) ? bo[0] : 0.f;
    b144[tid] = bv;
  }
}

// ---------------------------------------------------------------------------
// Kernel 2 (R14): MFMA bf16 split-precision GEMM. R5's VALU gemm was
// LDS/occupancy-bound at 306 µs with MfmaUtil=0 all session; work is only
// 8.9 GFLOP with 8x numerical slack (absmax 0.0019 vs threshold 0.0166).
// A*B = Ahi*Bhi + Ahi*Blo + Alo*Bhi in bf16 MFMA (fp32 accum): rel err
// ~2^-16, ~1e-3 absmax impact. One GEMM of N=132 (gates = cols 128-131).
// Per block: 128 rows x 144 cols (9 n-tiles) x K=256 in 8 chunks of 32.
// Fragment-ordered LDS (lane reads its own contiguous 16B) -> zero bank
// conflicts. 4 waves; wave w owns m-tiles {2w, 2w+1}; acc = 72 VGPR.
// Layouts (guide-verified): C/D col=lane&15,row=(lane>>4)*4+reg [m89];
// A row=lane&15,k=(lane>>4)*8+j; B col=lane&15, same k (B^T staged n-major).
// ---------------------------------------------------------------------------
__global__ __attribute__((amdgpu_waves_per_eu(1, 3))) __launch_bounds__(256)
void gemm_kernel(const float* __restrict__ X,
                 const unsigned short* __restrict__ Bth,
                 const unsigned short* __restrict__ Btl,
                 const float* __restrict__ bias144,
                 float* __restrict__ PRE) {
  __shared__ __align__(16) unsigned short Ah[4096];  // [mt4|kg][16 lane][8k]
  __shared__ __align__(16) unsigned short Al[4096];
  __shared__ __align__(16) unsigned short Bh[4608];  // [nt4|kg][16 lane][8k]
  __shared__ __align__(16) unsigned short Bl[4608];

  const int tid = threadIdx.x;
  const size_t rowbase = (size_t)blockIdx.x * 128;
  const int lane = tid & 63, wv = tid >> 6;
  const int l15 = lane & 15, kgl = lane >> 4;
  const int mt0 = wv * 2, mt1 = wv * 2 + 1;

  f32x4 acc0[9], acc1[9];
#pragma unroll
  for (int nt = 0; nt < 9; ++nt) {
    acc0[nt] = (f32x4){0.f, 0.f, 0.f, 0.f};
    acc1[nt] = (f32x4){0.f, 0.f, 0.f, 0.f};
  }

  for (int kc = 0; kc < 256; kc += 32) {
    __syncthreads();  // previous chunk's frag reads retired
    // ---- stage A: 512 frag-tasks (r 0..127 x kg 0..3), 2 per thread ----
#pragma unroll
    for (int s = 0; s < 2; ++s) {
      const int tau = tid + s * 256;
      const int r = tau >> 2, kg = tau & 3;
      const float4 xa = *(const float4*)&X[(rowbase + r) * 256 + kc + kg * 8];
      const float4 xb =
          *(const float4*)&X[(rowbase + r) * 256 + kc + kg * 8 + 4];
      unsigned short h0, h1, h2, h3, h4, h5, h6, h7;
      unsigned short l0, l1, l2, l3, l4, l5, l6, l7;
      cvt2(xa.x, h0, l0); cvt2(xa.y, h1, l1);
      cvt2(xa.z, h2, l2); cvt2(xa.w, h3, l3);
      cvt2(xb.x, h4, l4); cvt2(xb.y, h5, l5);
      cvt2(xb.z, h6, l6); cvt2(xb.w, h7, l7);
      const short8v hv = {(short)h0, (short)h1, (short)h2, (short)h3,
                          (short)h4, (short)h5, (short)h6, (short)h7};
      const short8v lv = {(short)l0, (short)l1, (short)l2, (short)l3,
                          (short)l4, (short)l5, (short)l6, (short)l7};
      const int dst = (((r >> 4) * 4 + kg) * 16 + (r & 15)) * 8;
      *(short8v*)&Ah[dst] = hv;
      *(short8v*)&Al[dst] = lv;
    }
    // ---- stage B: 576 frag-tasks (n 0..143 x kg 0..3), 16B copies ----
#pragma unroll
    for (int s = 0; s < 3; ++s) {
      const int tau = tid + s * 256;
      if (tau < 576) {
        const int n = tau >> 2, kg = tau & 3;
        const int src = n * 256 + kc + kg * 8;
        const int dst = (((n >> 4) * 4 + kg) * 16 + (n & 15)) * 8;
        *(short8v*)&Bh[dst] = *(const short8v*)&Bth[src];
        *(short8v*)&Bl[dst] = *(const short8v*)&Btl[src];
      }
    }
    __syncthreads();

    // ---- MFMA: my 2 m-tiles x 9 n-tiles x 3 split-terms ----
    const int ab0 = ((mt0 * 4 + kgl) * 16 + l15) * 8;
    const int ab1 = ((mt1 * 4 + kgl) * 16 + l15) * 8;
    const short8v ah0 = *(const short8v*)&Ah[ab0];
    const short8v al0 = *(const short8v*)&Al[ab0];
    const short8v ah1 = *(const short8v*)&Ah[ab1];
    const short8v al1 = *(const short8v*)&Al[ab1];
#pragma unroll
    for (int nt = 0; nt < 9; ++nt) {
      const int bb = ((nt * 4 + kgl) * 16 + l15) * 8;
      const short8v bh = *(const short8v*)&Bh[bb];
      const short8v bl = *(const short8v*)&Bl[bb];
      acc0[nt] = __builtin_amdgcn_mfma_f32_16x16x32_bf16(ah0, bh, acc0[nt], 0, 0, 0);
      acc0[nt] = __builtin_amdgcn_mfma_f32_16x16x32_bf16(ah0, bl, acc0[nt], 0, 0, 0);
      acc0[nt] = __builtin_amdgcn_mfma_f32_16x16x32_bf16(al0, bh, acc0[nt], 0, 0, 0);
      acc1[nt] = __builtin_amdgcn_mfma_f32_16x16x32_bf16(ah1, bh, acc1[nt], 0, 0, 0);
      acc1[nt] = __builtin_amdgcn_mfma_f32_16x16x32_bf16(ah1, bl, acc1[nt], 0, 0, 0);
      acc1[nt] = __builtin_amdgcn_mfma_f32_16x16x32_bf16(al1, bh, acc1[nt], 0, 0, 0);
    }
  }

  // ---- epilogue: bias + store (cols >= 132 masked; 132-135 = pad) ----
#pragma unroll
  for (int nt = 0; nt < 9; ++nt) {
    const int col = nt * 16 + l15;
    if (col < 132) {
      const float bb = bias144[col];
#pragma unroll
      for (int q = 0; q < 4; ++q) {
        PRE[(rowbase + mt0 * 16 + kgl * 4 + q) * PRE_STRIDE + col] =
            acc0[nt][q] + bb;
        PRE[(rowbase + mt1 * 16 + kgl * 4 + q) * PRE_STRIDE + col] =
            acc1[nt][q] + bb;
      }
    }
  }
}

// ---------------------------------------------------------------------------
// Kernel 3: serial recurrence — R13 version VERBATIM (proven 436.9 µs).
// ---------------------------------------------------------------------------
__device__ __forceinline__ float sigmoid_f(float x) {
  return __fdividef(1.0f, 1.0f + __expf(-x));
}
__device__ __forceinline__ float tanh_f(float x) {
  const float e = __expf(-2.0f * x);
  return __fdividef(1.0f - e, 1.0f + e);
}
__device__ __forceinline__ float readlane_f(float v, int lane) {
  return __int_as_float(__builtin_amdgcn_readlane(__float_as_int(v), lane));
}

__global__ __attribute__((amdgpu_waves_per_eu(1, 1))) __launch_bounds__(64)
void rec_kernel(
    const float* __restrict__ PRE, const float* __restrict__ W2,
    const float* __restrict__ b2, const float* __restrict__ aux,
    float* __restrict__ out) {
  __shared__ __align__(16) float h1s[128];

  const int l = threadIdx.x;
  const int b = blockIdx.x;
  const int m = l & 31, half = l >> 5;
  const int g = m >> 3;
  const int g8 = g * 8;

  float w2r[64];
#pragma unroll
  for (int u = 0; u < 64; ++u) w2r[u] = W2[(size_t)(half * 64 + u) * 32 + m];
  const float b2m = b2[m];
  const float2 s1 = *(const float2*)&aux[2 * l];
  const float4 sg = *(const float4*)&aux[128];

  float h = 0.f, c = 0.f;

  const float* pr0 = PRE + (size_t)b * PRE_STRIDE;
  const size_t ts = (size_t)BATCH * PRE_STRIDE;

  float2 p0 = *(const float2*)(pr0 + 0 * ts + 2 * l);
  float4 g0 = *(const float4*)(pr0 + 0 * ts + 128);
  float2 p1 = *(const float2*)(pr0 + 1 * ts + 2 * l);
  float4 g1 = *(const float4*)(pr0 + 1 * ts + 128);

  const float4* h1p = (const float4*)&h1s[half * 64];

  for (int t = 0; t < SEQ; ++t) {
    const float h10 = fmaxf(fmaf(h, s1.x, p0.x), 0.f);
    const float h11 = fmaxf(fmaf(h, s1.y, p0.y), 0.f);

    ((float2*)h1s)[l] = make_float2(h10, h11);
    asm volatile("" ::: "memory");

    const float zf = fmaf(h, sg.x, g0.x);
    const float zi = fmaf(h, sg.y, g0.y);
    const float zg = fmaf(h, sg.z, g0.z);
    const float zo = fmaf(h, sg.w, g0.w);
    const float cf = sigmoid_f(zf);
    const float ci = sigmoid_f(zi);
    const float cg = tanh_f(zg);
    const float co = sigmoid_f(zo);
    p0 = p1; g0 = g1;
    const int tn = (t + 2 < SEQ) ? (t + 2) : (SEQ - 1);
    p1 = *(const float2*)(pr0 + (size_t)tn * ts + 2 * l);
    g1 = *(const float4*)(pr0 + (size_t)tn * ts + 128);

    float q0 = 0.f, q1 = 0.f, q2 = 0.f, q3 = 0.f;
#pragma unroll
    for (int jj = 0; jj < 16; ++jj) {
      const float4 hv = h1p[jj];
      q0 = fmaf(hv.x, w2r[4 * jj + 0], q0);
      q1 = fmaf(hv.y, w2r[4 * jj + 1], q1);
      q2 = fmaf(hv.z, w2r[4 * jj + 2], q2);
      q3 = fmaf(hv.w, w2r[4 * jj + 3], q3);
    }
    const float part = (q0 + q1) + (q2 + q3);

    const float full = part + __shfl_xor(part, 32, 64);
    const float cm = __cosf(full + b2m);
    const int sb = (l & 32) + g8;
    const float e0 = __shfl(cm, sb + 0, 64);
    const float e1 = __shfl(cm, sb + 1, 64);
    const float e2 = __shfl(cm, sb + 2, 64);
    const float e3 = __shfl(cm, sb + 3, 64);
    const float e4 = __shfl(cm, sb + 4, 64);
    const float e5 = __shfl(cm, sb + 5, 64);
    const float e6 = __shfl(cm, sb + 6, 64);
    const float e7 = __shfl(cm, sb + 7, 64);
    float p = e0, s = e0;
    p *= e1; s += p;
    p *= e2; s += p;
    p *= e3; s += p;
    p *= e4; s += p;
    p *= e5; s += p;
    p *= e6; s += p;
    p *= e7; s += p;
    const float qv = s * 0.125f;

    const float qarg = (g == 2) ? (2.0f * qv) : qv;
    const float qs = sigmoid_f(qarg);
    const float av = (g == 2) ? (2.0f * qs - 1.0f) : qs;

    const float aF = readlane_f(av, 0);
    const float aI = readlane_f(av, 8);
    const float aG = readlane_f(av, 16);
    const float aO = readlane_f(av, 24);

    const float f  = 0.5f * (cf + aF);
    const float ii = 0.5f * (ci + aI);
    const float gg = 0.5f * (cg + aG);
    const float oo = 0.5f * (co + aO);

    c = fmaf(f, c, ii * gg);
    h = oo * tanh_f(c);

    float4 hv4o; hv4o.x = h; hv4o.y = h; hv4o.z = h; hv4o.w = h;
    *(float4*)(out + ((size_t)t * BATCH + b) * 256 + 4 * l) = hv4o;
  }

  float4 hq; hq.x = h; hq.y = h; hq.z = h; hq.w = h;
  float4 cq; cq.x = c; cq.y = c; cq.z = c; cq.w = c;
  *(float4*)(out + (size_t)SEQ * BATCH * 256 + (size_t)b * 256 + 4 * l) = hq;
  *(float4*)(out + (size_t)SEQ * BATCH * 256 + (size_t)BATCH * 256 +
             (size_t)b * 256 + 4 * l) = cq;
}

// ---------------------------------------------------------------------------
extern "C" void kernel_launch(void* const* d_in, const int* in_sizes, int n_in,
                              void* d_out, int out_size, void* d_ws,
                              size_t ws_size, hipStream_t stream) {
  const float* X  = (const float*)d_in[0];
  const float* W1 = (const float*)d_in[1];
  const float* b1 = (const float*)d_in[2];
  const float* W2 = (const float*)d_in[3];
  const float* b2 = (const float*)d_in[4];
  const float* Wf = (const float*)d_in[5];
  const float* bf = (const float*)d_in[6];
  const float* Wi = (const float*)d_in[7];
  const float* bi = (const float*)d_in[8];
  const float* Wg = (const float*)d_in[9];
  const float* bg = (const float*)d_in[10];
  const float* Wo = (const float*)d_in[11];
  const float* bo = (const float*)d_in[12];

  float* ws  = (float*)d_ws;
  float* PRE = ws;
  float* aux = ws + AUX_OFF;
  float* btbase = ws + BT_OFF;
  const unsigned short* bth = (const unsigned short*)btbase;
  const unsigned short* btl = (const unsigned short*)(btbase + 18432);
  const float* b144 = btbase + 36864;
  float* out = (float*)d_out;

  prep_kernel<<<1, 256, 0, stream>>>(W1, Wf, Wi, Wg, Wo, bf, bi, bg, bo,
                                     b1, aux, btbase);
  gemm_kernel<<<M_ROWS / 128, 256, 0, stream>>>(X, bth, btl, b144, PRE);
  rec_kernel<<<BATCH, 64, 0, stream>>>(PRE, W2, b2, aux, out);
}

// Round 9
// 703.966 us; speedup vs baseline: 1.1361x; 1.1361x over previous
//
#include <hip/hip_runtime.h>

#define SEQ 512
#define BATCH 256
#define INDIM 256
#define MLP 128
#define M_ROWS (SEQ * BATCH)        // 131072
#define PRE_STRIDE 136              // 128 mlp-pre + 4 gate-pre + 4 pad
#define AUX_OFF ((size_t)M_ROWS * PRE_STRIDE)  // in floats

// ws layout (floats): [0, AUX_OFF) PRE; [AUX_OFF, +136) aux;
// [BT_OFF ...) bf16 weight pairs: Bt_hi (18432 f = 36864 ushort),
// Bt_lo (18432 f), bias144 (144 f). Bt layout: [n(144)][k(256)] bf16,
// n<128 = W1 col n, n=128..131 = Wf/Wi/Wg/Wo input rows, n>=132 = 0.
#define BT_OFF (AUX_OFF + 160)

typedef __attribute__((ext_vector_type(8))) short short8v;
typedef __attribute__((ext_vector_type(4))) float f32x4;

__device__ __forceinline__ unsigned short bf16_rtne(float f) {
  unsigned u = __float_as_uint(f);
  unsigned r = u + 0x7FFFu + ((u >> 16) & 1u);
  return (unsigned short)(r >> 16);
}
__device__ __forceinline__ void cvt2(float f, unsigned short& h,
                                     unsigned short& l) {
  h = bf16_rtne(f);
  l = bf16_rtne(f - __uint_as_float((unsigned)h << 16));
}

// ---------------------------------------------------------------------------
// Kernel 1 (R15): prep parallelized — R14 ran the whole weight conversion on
// ONE block (36864 scalar strided loads + 73728 scattered 2B stores on one
// CU ~ 40-80 µs). Now 130 blocks:
//   block 0: aux col-sums + bias144 (as before).
//   block 1: gate rows n=128..131 (coalesced wg[k]) + zero pad n=132..143.
//   blocks 2..129: W1 rows k=2(b-2),2(b-2)+1 — thread (k2=tid>>7, n=tid&127)
//   reads W1[k][n] CONTIGUOUSLY (512B per 128 threads); 2B stores scatter,
//   but stores are fire-and-forget.
// ---------------------------------------------------------------------------
__global__ __launch_bounds__(256) void prep_kernel(
    const float* __restrict__ W1,
    const float* __restrict__ Wf, const float* __restrict__ Wi,
    const float* __restrict__ Wg, const float* __restrict__ Wo,
    const float* __restrict__ bf, const float* __restrict__ bi,
    const float* __restrict__ bg, const float* __restrict__ bo,
    const float* __restrict__ b1, float* __restrict__ aux,
    float* __restrict__ btbase) {
  const int tid = threadIdx.x;
  const int blk = blockIdx.x;
  unsigned short* bth = (unsigned short*)btbase;
  unsigned short* btl = (unsigned short*)(btbase + 18432);
  float* b144 = btbase + 36864;

  if (blk == 0) {
    if (tid < 128) {
      float s = 0.f;
      for (int k = 0; k < 256; ++k) s += W1[(size_t)(256 + k) * 128 + tid];
      aux[tid] = s;
    } else if (tid < 132) {
      const int g = tid - 128;
      const float* w = (g == 0) ? Wf : (g == 1) ? Wi : (g == 2) ? Wg : Wo;
      float s = 0.f;
      for (int k = 0; k < 256; ++k) s += w[256 + k];
      aux[128 + g] = s;
    } else if (tid < 136) {
      const int g = tid - 132;
      const float* bp = (g == 0) ? bf : (g == 1) ? bi : (g == 2) ? bg : bo;
      aux[132 + g] = bp[0];
    }
    if (tid < 144) {
      const float bv = (tid < 128) ? b1[tid]
                     : (tid == 128) ? bf[0] : (tid == 129) ? bi[0]
                     : (tid == 130) ? bg[0] : (tid == 131) ? bo[0] : 0.f;
      b144[tid] = bv;
    }
  } else if (blk == 1) {
    // gate rows n=128..131 (4 x 256 elements, coalesced source)
    for (int idx = tid; idx < 1024; idx += 256) {
      const int n = 128 + (idx >> 8), k = idx & 255;
      const float* wg = (n == 128) ? Wf : (n == 129) ? Wi
                       : (n == 130) ? Wg : Wo;
      unsigned short h, l;
      cvt2(wg[k], h, l);
      bth[n * 256 + k] = h;
      btl[n * 256 + k] = l;
    }
    // zero pad rows n=132..143
    for (int idx = tid; idx < 3072; idx += 256) {
      const int n = 132 + (idx >> 8), k = idx & 255;
      bth[n * 256 + k] = 0;
      btl[n * 256 + k] = 0;
    }
  } else {
    // W1 rows k = 2(blk-2), 2(blk-2)+1; coalesced row-major reads
    const int k = 2 * (blk - 2) + (tid >> 7);
    const int n = tid & 127;
    unsigned short h, l;
    cvt2(W1[(size_t)k * 128 + n], h, l);
    bth[n * 256 + k] = h;
    btl[n * 256 + k] = l;
  }
}

// ---------------------------------------------------------------------------
// Kernel 2 (R15): MFMA split-precision GEMM, re-blocked for register safety.
// R14 suspect: 128-row blocks -> acc 72 VGPR + heavy unrolled staging likely
// blew the 170-VGPR budget -> acc scratch-spill inside the MFMA loop (the
// R10 signature: MFMA kernel no faster than VALU). Now: 64 rows/block, ONE
// m-tile per wave -> acc[9] = 36 VGPR, frags 8, staging 1 task/thread;
// ~90-110 VGPR total under a waves_per_eu(1,4) budget of 128. LDS 26.6 KB
// -> 4+ blocks/CU co-resident hide the per-chunk staging latency. The MFMA
// sequence per output element is order-identical to R14 -> bitwise-same PRE.
// Layouts (guide-verified): C/D col=lane&15,row=(lane>>4)*4+reg [m89];
// A row=lane&15,k=(lane>>4)*8+j; B col=lane&15, same k (Bt staged n-major).
// Fragment-ordered LDS: each lane reads its own contiguous 16B -> 0 conflicts.
// ---------------------------------------------------------------------------
__global__ __attribute__((amdgpu_waves_per_eu(1, 4))) __launch_bounds__(256)
void gemm_kernel(const float* __restrict__ X,
                 const unsigned short* __restrict__ Bth,
                 const unsigned short* __restrict__ Btl,
                 const float* __restrict__ bias144,
                 float* __restrict__ PRE) {
  __shared__ __align__(16) unsigned short Ah[2048];  // [mt4|kg][16 lane][8k]
  __shared__ __align__(16) unsigned short Al[2048];
  __shared__ __align__(16) unsigned short Bh[4608];  // [nt9|kg][16 lane][8k]
  __shared__ __align__(16) unsigned short Bl[4608];

  const int tid = threadIdx.x;
  const size_t rowbase = (size_t)blockIdx.x * 64;
  const int lane = tid & 63, wv = tid >> 6;
  const int l15 = lane & 15, kgl = lane >> 4;

  f32x4 acc[9];
#pragma unroll
  for (int nt = 0; nt < 9; ++nt) acc[nt] = (f32x4){0.f, 0.f, 0.f, 0.f};

  for (int kc = 0; kc < 256; kc += 32) {
    __syncthreads();  // previous chunk's frag reads retired
    // ---- stage A: 256 frag-tasks (r 0..63 x kg 0..3), 1 per thread ----
    {
      const int r = tid >> 2, kg = tid & 3;
      const float4 xa = *(const float4*)&X[(rowbase + r) * 256 + kc + kg * 8];
      const float4 xb =
          *(const float4*)&X[(rowbase + r) * 256 + kc + kg * 8 + 4];
      unsigned short h0, h1, h2, h3, h4, h5, h6, h7;
      unsigned short l0, l1, l2, l3, l4, l5, l6, l7;
      cvt2(xa.x, h0, l0); cvt2(xa.y, h1, l1);
      cvt2(xa.z, h2, l2); cvt2(xa.w, h3, l3);
      cvt2(xb.x, h4, l4); cvt2(xb.y, h5, l5);
      cvt2(xb.z, h6, l6); cvt2(xb.w, h7, l7);
      const short8v hv = {(short)h0, (short)h1, (short)h2, (short)h3,
                          (short)h4, (short)h5, (short)h6, (short)h7};
      const short8v lv = {(short)l0, (short)l1, (short)l2, (short)l3,
                          (short)l4, (short)l5, (short)l6, (short)l7};
      const int dst = (((r >> 4) * 4 + kg) * 16 + (r & 15)) * 8;
      *(short8v*)&Ah[dst] = hv;
      *(short8v*)&Al[dst] = lv;
    }
    // ---- stage B: 576 frag-tasks (n 0..143 x kg 0..3), 16B copies ----
#pragma unroll
    for (int s = 0; s < 3; ++s) {
      const int tau = tid + s * 256;
      if (tau < 576) {
        const int n = tau >> 2, kg = tau & 3;
        const int src = n * 256 + kc + kg * 8;
        const int dst = (((n >> 4) * 4 + kg) * 16 + (n & 15)) * 8;
        *(short8v*)&Bh[dst] = *(const short8v*)&Bth[src];
        *(short8v*)&Bl[dst] = *(const short8v*)&Btl[src];
      }
    }
    __syncthreads();

    // ---- MFMA: my 1 m-tile x 9 n-tiles x 3 split-terms ----
    const int ab = ((wv * 4 + kgl) * 16 + l15) * 8;
    const short8v ah = *(const short8v*)&Ah[ab];
    const short8v al = *(const short8v*)&Al[ab];
#pragma unroll
    for (int nt = 0; nt < 9; ++nt) {
      const int bb = ((nt * 4 + kgl) * 16 + l15) * 8;
      const short8v bh = *(const short8v*)&Bh[bb];
      const short8v bl = *(const short8v*)&Bl[bb];
      acc[nt] = __builtin_amdgcn_mfma_f32_16x16x32_bf16(ah, bh, acc[nt], 0, 0, 0);
      acc[nt] = __builtin_amdgcn_mfma_f32_16x16x32_bf16(ah, bl, acc[nt], 0, 0, 0);
      acc[nt] = __builtin_amdgcn_mfma_f32_16x16x32_bf16(al, bh, acc[nt], 0, 0, 0);
    }
  }

  // ---- epilogue: bias + store (cols >= 132 masked; 132-143 = pad) ----
#pragma unroll
  for (int nt = 0; nt < 9; ++nt) {
    const int col = nt * 16 + l15;
    if (col < 132) {
      const float bb = bias144[col];
#pragma unroll
      for (int q = 0; q < 4; ++q) {
        PRE[(rowbase + wv * 16 + kgl * 4 + q) * PRE_STRIDE + col] =
            acc[nt][q] + bb;
      }
    }
  }
}

// ---------------------------------------------------------------------------
// Kernel 3: serial recurrence — R13 version VERBATIM (proven 436.9 µs).
// ---------------------------------------------------------------------------
__device__ __forceinline__ float sigmoid_f(float x) {
  return __fdividef(1.0f, 1.0f + __expf(-x));
}
__device__ __forceinline__ float tanh_f(float x) {
  const float e = __expf(-2.0f * x);
  return __fdividef(1.0f - e, 1.0f + e);
}
__device__ __forceinline__ float readlane_f(float v, int lane) {
  return __int_as_float(__builtin_amdgcn_readlane(__float_as_int(v), lane));
}

__global__ __attribute__((amdgpu_waves_per_eu(1, 1))) __launch_bounds__(64)
void rec_kernel(
    const float* __restrict__ PRE, const float* __restrict__ W2,
    const float* __restrict__ b2, const float* __restrict__ aux,
    float* __restrict__ out) {
  __shared__ __align__(16) float h1s[128];

  const int l = threadIdx.x;
  const int b = blockIdx.x;
  const int m = l & 31, half = l >> 5;
  const int g = m >> 3;
  const int g8 = g * 8;

  float w2r[64];
#pragma unroll
  for (int u = 0; u < 64; ++u) w2r[u] = W2[(size_t)(half * 64 + u) * 32 + m];
  const float b2m = b2[m];
  const float2 s1 = *(const float2*)&aux[2 * l];
  const float4 sg = *(const float4*)&aux[128];

  float h = 0.f, c = 0.f;

  const float* pr0 = PRE + (size_t)b * PRE_STRIDE;
  const size_t ts = (size_t)BATCH * PRE_STRIDE;

  float2 p0 = *(const float2*)(pr0 + 0 * ts + 2 * l);
  float4 g0 = *(const float4*)(pr0 + 0 * ts + 128);
  float2 p1 = *(const float2*)(pr0 + 1 * ts + 2 * l);
  float4 g1 = *(const float4*)(pr0 + 1 * ts + 128);

  const float4* h1p = (const float4*)&h1s[half * 64];

  for (int t = 0; t < SEQ; ++t) {
    const float h10 = fmaxf(fmaf(h, s1.x, p0.x), 0.f);
    const float h11 = fmaxf(fmaf(h, s1.y, p0.y), 0.f);

    ((float2*)h1s)[l] = make_float2(h10, h11);
    asm volatile("" ::: "memory");

    const float zf = fmaf(h, sg.x, g0.x);
    const float zi = fmaf(h, sg.y, g0.y);
    const float zg = fmaf(h, sg.z, g0.z);
    const float zo = fmaf(h, sg.w, g0.w);
    const float cf = sigmoid_f(zf);
    const float ci = sigmoid_f(zi);
    const float cg = tanh_f(zg);
    const float co = sigmoid_f(zo);
    p0 = p1; g0 = g1;
    const int tn = (t + 2 < SEQ) ? (t + 2) : (SEQ - 1);
    p1 = *(const float2*)(pr0 + (size_t)tn * ts + 2 * l);
    g1 = *(const float4*)(pr0 + (size_t)tn * ts + 128);

    float q0 = 0.f, q1 = 0.f, q2 = 0.f, q3 = 0.f;
#pragma unroll
    for (int jj = 0; jj < 16; ++jj) {
      const float4 hv = h1p[jj];
      q0 = fmaf(hv.x, w2r[4 * jj + 0], q0);
      q1 = fmaf(hv.y, w2r[4 * jj + 1], q1);
      q2 = fmaf(hv.z, w2r[4 * jj + 2], q2);
      q3 = fmaf(hv.w, w2r[4 * jj + 3], q3);
    }
    const float part = (q0 + q1) + (q2 + q3);

    const float full = part + __shfl_xor(part, 32, 64);
    const float cm = __cosf(full + b2m);
    const int sb = (l & 32) + g8;
    const float e0 = __shfl(cm, sb + 0, 64);
    const float e1 = __shfl(cm, sb + 1, 64);
    const float e2 = __shfl(cm, sb + 2, 64);
    const float e3 = __shfl(cm, sb + 3, 64);
    const float e4 = __shfl(cm, sb + 4, 64);
    const float e5 = __shfl(cm, sb + 5, 64);
    const float e6 = __shfl(cm, sb + 6, 64);
    const float e7 = __shfl(cm, sb + 7, 64);
    float p = e0, s = e0;
    p *= e1; s += p;
    p *= e2; s += p;
    p *= e3; s += p;
    p *= e4; s += p;
    p *= e5; s += p;
    p *= e6; s += p;
    p *= e7; s += p;
    const float qv = s * 0.125f;

    const float qarg = (g == 2) ? (2.0f * qv) : qv;
    const float qs = sigmoid_f(qarg);
    const float av = (g == 2) ? (2.0f * qs - 1.0f) : qs;

    const float aF = readlane_f(av, 0);
    const float aI = readlane_f(av, 8);
    const float aG = readlane_f(av, 16);
    const float aO = readlane_f(av, 24);

    const float f  = 0.5f * (cf + aF);
    const float ii = 0.5f * (ci + aI);
    const float gg = 0.5f * (cg + aG);
    const float oo = 0.5f * (co + aO);

    c = fmaf(f, c, ii * gg);
    h = oo * tanh_f(c);

    float4 hv4o; hv4o.x = h; hv4o.y = h; hv4o.z = h; hv4o.w = h;
    *(float4*)(out + ((size_t)t * BATCH + b) * 256 + 4 * l) = hv4o;
  }

  float4 hq; hq.x = h; hq.y = h; hq.z = h; hq.w = h;
  float4 cq; cq.x = c; cq.y = c; cq.z = c; cq.w = c;
  *(float4*)(out + (size_t)SEQ * BATCH * 256 + (size_t)b * 256 + 4 * l) = hq;
  *(float4*)(out + (size_t)SEQ * BATCH * 256 + (size_t)BATCH * 256 +
             (size_t)b * 256 + 4 * l) = cq;
}

// ---------------------------------------------------------------------------
extern "C" void kernel_launch(void* const* d_in, const int* in_sizes, int n_in,
                              void* d_out, int out_size, void* d_ws,
                              size_t ws_size, hipStream_t stream) {
  const float* X  = (const float*)d_in[0];
  const float* W1 = (const float*)d_in[1];
  const float* b1 = (const float*)d_in[2];
  const float* W2 = (const float*)d_in[3];
  const float* b2 = (const float*)d_in[4];
  const float* Wf = (const float*)d_in[5];
  const float* bf = (const float*)d_in[6];
  const float* Wi = (const float*)d_in[7];
  const float* bi = (const float*)d_in[8];
  const float* Wg = (const float*)d_in[9];
  const float* bg = (const float*)d_in[10];
  const float* Wo = (const float*)d_in[11];
  const float* bo = (const float*)d_in[12];

  float* ws  = (float*)d_ws;
  float* PRE = ws;
  float* aux = ws + AUX_OFF;
  float* btbase = ws + BT_OFF;
  const unsigned short* bth = (const unsigned short*)btbase;
  const unsigned short* btl = (const unsigned short*)(btbase + 18432);
  const float* b144 = btbase + 36864;
  float* out = (float*)d_out;

  prep_kernel<<<130, 256, 0, stream>>>(W1, Wf, Wi, Wg, Wo, bf, bi, bg, bo,
                                       b1, aux, btbase);
  gemm_kernel<<<M_ROWS / 64, 256, 0, stream>>>(X, bth, btl, b144, PRE);
  rec_kernel<<<BATCH, 64, 0, stream>>>(PRE, W2, b2, aux, out);
}